// Round 2
// baseline (65.891 us; speedup 1.0000x reference)
//
#include <hip/hip_runtime.h>
#include <math.h>

#define K_SIZE 5
#define EPS    1e-6f
#define EPS_L  1e-3f
#define EPS_W  1e-3f

#define BATCH 4
#define HGT   512
#define WID   512
#define HW    (HGT * WID)

__global__ __launch_bounds__(256) void fused_sample_kernel(
    const float* __restrict__ input,   // (B,1,H,W)
    const float* __restrict__ Lp,      // (B,H,W,3)
    const float* __restrict__ wbuf,    // (B,2,H,W)
    float* __restrict__ out)           // (B,1,H,W)
{
#pragma clang fp contract(off)
    int idx = blockIdx.x * blockDim.x + threadIdx.x;
    const int total = BATCH * HW;
    if (idx >= total) return;

    const int b = idx >> 18;            // / (512*512)
    const int p = idx & (HW - 1);
    const int y = p >> 9;
    const int x = p & (WID - 1);

    const float* __restrict__ img = input + (size_t)b * HW;

    // ---- per-pixel matrix (all ops mirror the numpy reference order) ----
    const size_t l_off = (size_t)idx * 3;
    const float L0 = Lp[l_off + 0];
    const float L1 = Lp[l_off + 1];
    const float L2 = Lp[l_off + 2];

    const float a  = fabsf(L0) + EPS_L;
    const float bb = L1;
    const float c  = fabsf(L2) + EPS_L;

    const float M00 = a * a;
    const float M01 = a * bb;
    const float M11 = (bb * bb) + (c * c);

    const float d00 = M00 + EPS;
    const float d11 = M11 + EPS;
    const float det = (d00 * d11) - (M01 * M01);
    const float I00 = d11 / det;          // IEEE f32 div, same as np
    const float I01 = (-M01) / det;
    const float I11 = d00 / det;

    const float wx = wbuf[(size_t)b * 2 * HW + p];
    const float wy = wbuf[(size_t)b * 2 * HW + HW + p];

    // q = I00*wx*wx + 2*I01*wx*wy + I11*wy*wy, left-assoc like python
    const float q    = (((I00 * wx) * wx) + (((2.0f * I01) * wx) * wy)) + ((I11 * wy) * wy);
    const float norm = sqrtf(q + EPS);

    // sigmoid(norm) = 1/(1+exp(-norm)); exp in double -> correctly-rounded f32
    const float e    = (float)exp((double)(-norm));
    const float sig  = 1.0f / (1.0f + e);
    const float tuned = ((sig - 0.5f) * 2.0f) * (1.0f - EPS_W);
    const float scale = tuned / (norm + EPS);      // IEEE div
    const float wtx = wx * scale;
    const float wty = wy * scale;

    // cos/sin of the FLOAT32-ROUNDED theta_k (what jnp.arange+cos/sin produce)
    const float CT[K_SIZE] = { 1.0f,  0.30901696090f, -0.80901703575f, -0.80901693229f,  0.30901712828f };
    const float ST[K_SIZE] = { 0.0f,  0.95105652717f,  0.58778519534f, -0.58778533774f, -0.95105647279f };
    const float SV[K_SIZE] = { 0.2f, 0.4f, 0.6f, 0.8f, 1.0f };

    const float fy = (float)y;
    const float fx = (float)x;

    float acc = 0.0f;

    #pragma unroll
    for (int k = 0; k < K_SIZE; ++k) {
        const float ct = CT[k];
        const float st = ST[k];
        // quad = M00*ct*ct + 2*M01*ct*st + M11*st*st (left-assoc)
        const float quad = (((M00 * ct) * ct) + (((2.0f * M01) * ct) * st)) + ((M11 * st) * st);
        const float F    = (sqrtf(quad) + (wtx * ct)) + (wty * st);
        const float Fe   = F + EPS;
        const float yx   = ct / Fe;       // IEEE div, matches np
        const float yy   = st / Fe;

        #pragma unroll
        for (int s = 0; s < K_SIZE; ++s) {
            const float sv = SV[s];
            const float gy = fy + (sv * yy);
            const float gx = fx + (sv * yx);

            const float fy0 = floorf(gy);
            const float fx0 = floorf(gx);
            const float wyf = gy - fy0;
            const float wxf = gx - fx0;

            float val = 0.0f;
            // corner weights computed first, then img*wgt (reference order)
            {
                const float yc = fy0, xc = fx0;
                if (yc >= 0.0f && yc <= (float)(HGT - 1) && xc >= 0.0f && xc <= (float)(WID - 1)) {
                    const float wgt = (1.0f - wyf) * (1.0f - wxf);
                    val = val + img[(int)yc * WID + (int)xc] * wgt;
                }
            }
            {
                const float yc = fy0, xc = fx0 + 1.0f;
                if (yc >= 0.0f && yc <= (float)(HGT - 1) && xc >= 0.0f && xc <= (float)(WID - 1)) {
                    const float wgt = (1.0f - wyf) * wxf;
                    val = val + img[(int)yc * WID + (int)xc] * wgt;
                }
            }
            {
                const float yc = fy0 + 1.0f, xc = fx0;
                if (yc >= 0.0f && yc <= (float)(HGT - 1) && xc >= 0.0f && xc <= (float)(WID - 1)) {
                    const float wgt = wyf * (1.0f - wxf);
                    val = val + img[(int)yc * WID + (int)xc] * wgt;
                }
            }
            {
                const float yc = fy0 + 1.0f, xc = fx0 + 1.0f;
                if (yc >= 0.0f && yc <= (float)(HGT - 1) && xc >= 0.0f && xc <= (float)(WID - 1)) {
                    const float wgt = wyf * wxf;
                    val = val + img[(int)yc * WID + (int)xc] * wgt;
                }
            }
            acc = acc + val;
        }
    }

    out[idx] = acc / (float)(K_SIZE * K_SIZE);
}

extern "C" void kernel_launch(void* const* d_in, const int* in_sizes, int n_in,
                              void* d_out, int out_size, void* d_ws, size_t ws_size,
                              hipStream_t stream) {
    const float* input = (const float*)d_in[0];
    const float* Lp    = (const float*)d_in[1];
    const float* wbuf  = (const float*)d_in[2];
    float* out = (float*)d_out;

    const int total = BATCH * HW;            // 1,048,576
    const int block = 256;
    const int grid  = (total + block - 1) / block;   // 4096
    fused_sample_kernel<<<grid, block, 0, stream>>>(input, Lp, wbuf, out);
}

// Round 3
// 55.145 us; speedup vs baseline: 1.1949x; 1.1949x over previous
//
#include <hip/hip_runtime.h>
#include <math.h>

#define K_SIZE 5
#define EPS    1e-6f
#define EPS_L  1e-3f
#define EPS_W  1e-3f

#define BATCH 4
#define HGT   512
#define WID   512
#define HW    (HGT * WID)

__global__ __launch_bounds__(256) void fused_sample_kernel(
    const float* __restrict__ input,   // (B,1,H,W)
    const float* __restrict__ Lp,      // (B,H,W,3)
    const float* __restrict__ wbuf,    // (B,2,H,W)
    float* __restrict__ out)           // (B,1,H,W)
{
#pragma clang fp contract(off)
    int idx = blockIdx.x * blockDim.x + threadIdx.x;
    const int total = BATCH * HW;
    if (idx >= total) return;

    const int b = idx >> 18;            // / (512*512)
    const int p = idx & (HW - 1);
    const int y = p >> 9;
    const int x = p & (WID - 1);

    const float* __restrict__ img = input + (size_t)b * HW;

    // ---- per-pixel matrix (exactly mirrors numpy op order; amplified path) ----
    const size_t l_off = (size_t)idx * 3;
    const float L0 = Lp[l_off + 0];
    const float L1 = Lp[l_off + 1];
    const float L2 = Lp[l_off + 2];

    const float a  = fabsf(L0) + EPS_L;
    const float bb = L1;
    const float c  = fabsf(L2) + EPS_L;

    const float M00 = a * a;
    const float M01 = a * bb;
    const float M11 = (bb * bb) + (c * c);

    const float d00 = M00 + EPS;
    const float d11 = M11 + EPS;
    const float det = (d00 * d11) - (M01 * M01);
    const float I00 = d11 / det;          // IEEE f32 div, same as np
    const float I01 = (-M01) / det;
    const float I11 = d00 / det;

    const float wx = wbuf[(size_t)b * 2 * HW + p];
    const float wy = wbuf[(size_t)b * 2 * HW + HW + p];

    const float q    = (((I00 * wx) * wx) + (((2.0f * I01) * wx) * wy)) + ((I11 * wy) * wy);
    const float norm = sqrtf(q + EPS);

    const float e    = (float)exp((double)(-norm));   // correctly-rounded f32 exp
    const float sig  = 1.0f / (1.0f + e);
    const float tuned = ((sig - 0.5f) * 2.0f) * (1.0f - EPS_W);
    const float scale = tuned / (norm + EPS);         // IEEE div
    const float wtx = wx * scale;
    const float wty = wy * scale;

    // cos/sin of the FLOAT32-ROUNDED theta_k
    const float CT[K_SIZE] = { 1.0f,  0.30901696090f, -0.80901703575f, -0.80901693229f,  0.30901712828f };
    const float ST[K_SIZE] = { 0.0f,  0.95105652717f,  0.58778519534f, -0.58778533774f, -0.95105647279f };
    const float SV[K_SIZE] = { 0.2f, 0.4f, 0.6f, 0.8f, 1.0f };

    const float fy = (float)y;
    const float fx = (float)x;

    float acc = 0.0f;

    #pragma unroll
    for (int k = 0; k < K_SIZE; ++k) {
        const float ct = CT[k];
        const float st = ST[k];
        // amplified path: keep exact left-assoc, no contraction
        const float quad = (((M00 * ct) * ct) + (((2.0f * M01) * ct) * st)) + ((M11 * st) * st);
        const float F    = (sqrtf(quad) + (wtx * ct)) + (wty * st);
        const float Fe   = F + EPS;
        // downstream of the cancellation: approx rcp is safe (error not amplified)
        const float rFe  = __builtin_amdgcn_rcpf(Fe);
        const float yx   = ct * rFe;
        const float yy   = st * rFe;

        #pragma unroll
        for (int s = 0; s < K_SIZE; ++s) {
            const float sv = SV[s];
            const float gy = fmaf(sv, yy, fy);
            const float gx = fmaf(sv, yx, fx);

            const float fy0 = floorf(gy);
            const float fx0 = floorf(gx);
            const float wyf = gy - fy0;
            const float wxf = gx - fx0;

            const int y0i = (int)fy0;          // v_cvt_i32_f32 saturates; fine
            const int x0i = (int)fx0;
            const int y1i = y0i + 1;
            const int x1i = x0i + 1;

            const bool vy0 = (unsigned)y0i < (unsigned)HGT;
            const bool vy1 = (unsigned)y1i < (unsigned)HGT;
            const bool vx0 = (unsigned)x0i < (unsigned)WID;
            const bool vx1 = (unsigned)x1i < (unsigned)WID;

            const int y0c = min(max(y0i, 0), HGT - 1);
            const int y1c = min(max(y1i, 0), HGT - 1);
            const int x0c = min(max(x0i, 0), WID - 1);
            const int x1c = min(max(x1i, 0), WID - 1);

            const int r0 = y0c << 9;
            const int r1 = y1c << 9;

            const float v00 = img[r0 + x0c];
            const float v01 = img[r0 + x1c];
            const float v10 = img[r1 + x0c];
            const float v11 = img[r1 + x1c];

            const float wy0 = 1.0f - wyf;
            const float wx0v = 1.0f - wxf;

            const float w00 = (vy0 && vx0) ? (wy0 * wx0v) : 0.0f;
            const float w01 = (vy0 && vx1) ? (wy0 * wxf ) : 0.0f;
            const float w10 = (vy1 && vx0) ? (wyf * wx0v) : 0.0f;
            const float w11 = (vy1 && vx1) ? (wyf * wxf ) : 0.0f;

            acc = fmaf(v00, w00, acc);
            acc = fmaf(v01, w01, acc);
            acc = fmaf(v10, w10, acc);
            acc = fmaf(v11, w11, acc);
        }
    }

    out[idx] = acc / (float)(K_SIZE * K_SIZE);
}

extern "C" void kernel_launch(void* const* d_in, const int* in_sizes, int n_in,
                              void* d_out, int out_size, void* d_ws, size_t ws_size,
                              hipStream_t stream) {
    const float* input = (const float*)d_in[0];
    const float* Lp    = (const float*)d_in[1];
    const float* wbuf  = (const float*)d_in[2];
    float* out = (float*)d_out;

    const int total = BATCH * HW;            // 1,048,576
    const int block = 256;
    const int grid  = (total + block - 1) / block;   // 4096
    fused_sample_kernel<<<grid, block, 0, stream>>>(input, Lp, wbuf, out);
}